// Round 11
// baseline (309.362 us; speedup 1.0000x reference)
//
#include <hip/hip_runtime.h>

#define AS1 __attribute__((address_space(1)))
#define AS3 __attribute__((address_space(3)))

typedef __attribute__((ext_vector_type(8))) _Float16 f16x8;
typedef __attribute__((ext_vector_type(4))) _Float16 f16x4;
typedef __attribute__((ext_vector_type(4))) float f32x4;

#define MFMA_K16(a, b, c) __builtin_amdgcn_mfma_f32_16x16x16f16(a, b, c, 0, 0, 0)

__device__ __forceinline__ unsigned short f2h(float f) {
    union { _Float16 h; unsigned short u; } v; v.h = (_Float16)f; return v.u;
}

__device__ __forceinline__ void gload16(const void* g, void* l) {
    __builtin_amdgcn_global_load_lds((const AS1 unsigned int*)g, (AS3 unsigned int*)l, 16, 0, 0);
}

#define GBAR() __builtin_amdgcn_s_barrier()
#define VM4()  asm volatile("s_waitcnt vmcnt(4)" ::: "memory")
#define VM0()  asm volatile("s_waitcnt vmcnt(0)" ::: "memory")

// ---------- fused prep: x->fp16 cvt (z=24), Wq/Wk/Wv transposes (z<16), Wo transpose (z 16..23) ----------
__global__ __launch_bounds__(256) void k_prep(const float* __restrict__ x,
                                              const float* __restrict__ Wq,
                                              const float* __restrict__ Wk,
                                              const float* __restrict__ Wv,
                                              const float* __restrict__ Wo,
                                              unsigned short* __restrict__ xh,
                                              unsigned short* __restrict__ WT,
                                              unsigned short* __restrict__ WoT) {
    int z = blockIdx.z;
    if (z == 24) {   // x cvt: 2M float4 over 512 blocks x 256 thr x 16 iters
        int blk = blockIdx.y * 8 + blockIdx.x;
        int t = threadIdx.y * 32 + threadIdx.x;
        const float4* s4 = (const float4*)x;
        ushort4* d4 = (ushort4*)xh;
        int base = blk * 4096 + t;
#pragma unroll
        for (int i = 0; i < 16; i++) {
            float4 v = s4[base + i * 256];
            ushort4 u;
            u.x = f2h(v.x); u.y = f2h(v.y); u.z = f2h(v.z); u.w = f2h(v.w);
            d4[base + i * 256] = u;
        }
        return;
    }
    const float* src; unsigned short* dst;
    int ld_src, c0, r0;
    if (z < 16) {   // qkv weights: dst[c][r] layout rows: q 0..2047, k 2048..3071, v 3072..4095
        if (z < 8)       { src = Wq + (size_t)z * 524288;        dst = WT + (size_t)z * 524288; }
        else if (z < 12) { src = Wk + (size_t)(z - 8) * 524288;  dst = WT + (size_t)2048 * 2048 + (size_t)(z - 8) * 524288; }
        else             { src = Wv + (size_t)(z - 12) * 524288; dst = WT + (size_t)3072 * 2048 + (size_t)(z - 12) * 524288; }
        ld_src = 256;
        c0 = blockIdx.x * 32; r0 = blockIdx.y * 32;
    } else {        // Wo (2048x2048)
        src = Wo; dst = WoT; ld_src = 2048;
        c0 = ((z - 16) * 8 + blockIdx.x) * 32; r0 = blockIdx.y * 32;
    }
    __shared__ float tile[32][33];
    int tx = threadIdx.x, ty = threadIdx.y;
#pragma unroll
    for (int i = 0; i < 4; i++)
        tile[ty + i * 8][tx] = src[(size_t)(r0 + ty + i * 8) * ld_src + c0 + tx];
    __syncthreads();
#pragma unroll
    for (int i = 0; i < 4; i++)
        dst[(size_t)(c0 + ty + i * 8) * 2048 + r0 + tx] = f2h(tile[tx][ty + i * 8]);
}

// ---------- tiled transpose + convert (for V): dst[c*ld_dst + r] = fp16(src[r*ld_src + c]) ----------
__global__ __launch_bounds__(256) void k_transpose_cvt(const float* __restrict__ src,
                                                       unsigned short* __restrict__ dst,
                                                       int ld_src, int ld_dst,
                                                       long zs_src, long zs_dst) {
    __shared__ float tile[32][33];
    long sb = (long)blockIdx.z * zs_src;
    long db = (long)blockIdx.z * zs_dst;
    int c0 = blockIdx.x * 32, r0 = blockIdx.y * 32;
    int tx = threadIdx.x, ty = threadIdx.y;
#pragma unroll
    for (int i = 0; i < 4; i++)
        tile[ty + i * 8][tx] = src[sb + (long)(r0 + ty + i * 8) * ld_src + c0 + tx];
    __syncthreads();
#pragma unroll
    for (int i = 0; i < 4; i++)
        dst[db + (long)(c0 + ty + i * 8) * ld_dst + r0 + tx] = f2h(tile[tx][ty + i * 8]);
}

// ======== 256x256 8-phase fp16 GEMM (T2+T3+T4+T5): C = A(MxK) * Bt(NxK)^T, f32 out ========
template<int BUF, int MIH>
__device__ __forceinline__ void rdA(const unsigned short* SA, int wm, int fr, int g,
                                    f16x8 (&af)[4][2]) {
#pragma unroll
    for (int m = 0; m < 4; m++)
#pragma unroll
        for (int kk = 0; kk < 2; kk++) {
            int pos = wm * 64 + m * 16 + fr;
            af[m][kk] = *(const f16x8*)(SA + BUF * 16384 + MIH * 8192 + pos * 64 +
                                        (((kk * 4 + g) ^ (fr & 7)) << 3));
        }
}

template<int BUF, int NIH>
__device__ __forceinline__ void rdB(const unsigned short* SB, int wn, int fr, int g,
                                    f16x8 (&bf)[2][2]) {
#pragma unroll
    for (int ni2 = 0; ni2 < 2; ni2++)
#pragma unroll
        for (int kk = 0; kk < 2; kk++) {
            int pos = wn * 32 + ni2 * 16 + fr;
            bf[ni2][kk] = *(const f16x8*)(SB + BUF * 16384 + NIH * 8192 + pos * 64 +
                                          (((kk * 4 + g) ^ (fr & 7)) << 3));
        }
}

template<int MIH, int NIH>
__device__ __forceinline__ void mm16(f16x8 (&af)[4][2], f16x8 (&bf)[2][2], f32x4 (&acc)[8][4]) {
    __builtin_amdgcn_s_setprio(1);
#pragma unroll
    for (int m = 0; m < 4; m++)
#pragma unroll
        for (int ni2 = 0; ni2 < 2; ni2++)
#pragma unroll
            for (int kk = 0; kk < 2; kk++)
                acc[MIH * 4 + m][NIH * 2 + ni2] = __builtin_amdgcn_mfma_f32_16x16x32_f16(
                    af[m][kk], bf[ni2][kk], acc[MIH * 4 + m][NIH * 2 + ni2], 0, 0, 0);
    __builtin_amdgcn_s_setprio(0);
}

__global__ __launch_bounds__(512, 1) void k_gemm256(const unsigned short* __restrict__ A,
                                                    const unsigned short* __restrict__ Bt,
                                                    float* __restrict__ C,
                                                    int M, int N, int K, int nbx) {
    __shared__ __align__(16) unsigned short sm[65536];   // 128 KB
    unsigned short* SA = sm;
    unsigned short* SB = sm + 32768;

    int tid = threadIdx.x, lane = tid & 63, wid = tid >> 6;
    int g = lane >> 4, fr = lane & 15;
    int wm = wid >> 2, wn = wid & 3;

    int bid = blockIdx.x;
    int sid = (bid & 7) * ((int)gridDim.x >> 3) + (bid >> 3);
    int by = sid / nbx, bx = sid % nbx;
    int rowA0 = by * 256, colB0 = bx * 256;

    f32x4 acc[8][4];
#pragma unroll
    for (int mi = 0; mi < 8; mi++)
#pragma unroll
        for (int ni = 0; ni < 4; ni++) acc[mi][ni] = (f32x4){0.f, 0.f, 0.f, 0.f};

    auto stA = [&](int buf, int h, int kt) {
#pragma unroll
        for (int t = 0; t < 2; t++) {
            int i = t * 512 + tid;
            int pos = i >> 3;
            int grow = rowA0 + ((pos >> 6) << 7) + h * 64 + (pos & 63);
            int cg = (i & 7) ^ (pos & 7);
            gload16(A + (size_t)grow * K + kt * 64 + cg * 8,
                    SA + buf * 16384 + h * 8192 + pos * 64 + (i & 7) * 8);
        }
    };
    auto stB = [&](int buf, int h, int kt) {
#pragma unroll
        for (int t = 0; t < 2; t++) {
            int i = t * 512 + tid;
            int pos = i >> 3;
            int gcol = colB0 + ((pos >> 5) << 6) + h * 32 + (pos & 31);
            int cg = (i & 7) ^ (pos & 7);
            gload16(Bt + (size_t)gcol * K + kt * 64 + cg * 8,
                    SB + buf * 16384 + h * 8192 + pos * 64 + (i & 7) * 8);
        }
    };

    int nT = K >> 6;
    stA(0, 0, 0); stB(0, 0, 0); stA(0, 1, 0); stB(0, 1, 0);
    stA(1, 0, 1); stB(1, 0, 1);
    VM4();
    GBAR();

    f16x8 af[4][2], bf[2][2];
    int nIt = nT >> 1;
    for (int it = 0; it < nIt; it++) {
        int T = it * 2;
        bool s36 = (T + 2 < nT), s78 = (T + 3 < nT);
        rdA<0, 0>(SA, wm, fr, g, af); rdB<0, 0>(SB, wn, fr, g, bf);
        stA(1, 1, T + 1);
        GBAR(); mm16<0, 0>(af, bf, acc); GBAR();
        rdB<0, 1>(SB, wn, fr, g, bf);
        stB(1, 1, T + 1);
        GBAR(); mm16<0, 1>(af, bf, acc); GBAR();
        rdA<0, 1>(SA, wm, fr, g, af); rdB<0, 0>(SB, wn, fr, g, bf);
        if (s36) stA(0, 0, T + 2);
        GBAR(); mm16<1, 0>(af, bf, acc); GBAR();
        rdB<0, 1>(SB, wn, fr, g, bf);
        if (s36) { stB(0, 0, T + 2); VM4(); } else { VM0(); }
        GBAR(); mm16<1, 1>(af, bf, acc); GBAR();
        rdA<1, 0>(SA, wm, fr, g, af); rdB<1, 0>(SB, wn, fr, g, bf);
        if (s36) stA(0, 1, T + 2);
        GBAR(); mm16<0, 0>(af, bf, acc); GBAR();
        rdB<1, 1>(SB, wn, fr, g, bf);
        if (s36) stB(0, 1, T + 2);
        GBAR(); mm16<0, 1>(af, bf, acc); GBAR();
        rdA<1, 1>(SA, wm, fr, g, af); rdB<1, 0>(SB, wn, fr, g, bf);
        if (s78) stA(1, 0, T + 3);
        GBAR(); mm16<1, 0>(af, bf, acc); GBAR();
        rdB<1, 1>(SB, wn, fr, g, bf);
        if (s78) { stB(1, 0, T + 3); VM4(); } else { VM0(); }
        GBAR(); mm16<1, 1>(af, bf, acc); GBAR();
    }

#pragma unroll
    for (int mi = 0; mi < 8; mi++) {
        int row = rowA0 + wm * 128 + mi * 16 + g * 4;
#pragma unroll
        for (int ni = 0; ni < 4; ni++) {
            int col = colB0 + wn * 64 + ni * 16 + fr;
#pragma unroll
            for (int r = 0; r < 4; r++)
                C[(size_t)(row + r) * N + col] = acc[mi][ni][r];
        }
    }
}

// ---------- fp16 GEMM (out-proj): C = A(MxK) * Bt(NxK)^T, f32 out. 128x128 tile ----------
__global__ __launch_bounds__(256) void k_gemm_f16(const unsigned short* __restrict__ A,
                                                  const unsigned short* __restrict__ Bt,
                                                  float* __restrict__ C,
                                                  int M, int N, int K) {
    __shared__ unsigned short As[128 * 64];
    __shared__ unsigned short Bs[128 * 64];
    int tid = threadIdx.x;
    int lane = tid & 63, wid = tid >> 6;
    int g = lane >> 4, fr = lane & 15;
    int rowA0 = blockIdx.y * 128;
    int colB0 = blockIdx.x * 128;

    f32x4 zero = {0.f, 0.f, 0.f, 0.f};
    f32x4 acc[4][4];
#pragma unroll
    for (int mi = 0; mi < 4; mi++)
#pragma unroll
        for (int ni = 0; ni < 4; ni++) acc[mi][ni] = zero;

    const unsigned short* ag[4];
    const unsigned short* bg[4];
#pragma unroll
    for (int j = 0; j < 4; j++) {
        int id = j * 256 + tid;
        int r = id >> 3;
        int c = (id & 7) ^ (r & 7);
        ag[j] = A + (size_t)(rowA0 + r) * K + c * 8;
        bg[j] = Bt + (size_t)(colB0 + r) * K + c * 8;
    }

    int nK = K >> 6;
    for (int kt = 0; kt < nK; kt++) {
#pragma unroll
        for (int j = 0; j < 4; j++) {
            int id = j * 256 + tid;
            gload16(ag[j], As + id * 8);
            gload16(bg[j], Bs + id * 8);
            ag[j] += 64; bg[j] += 64;
        }
        __syncthreads();
#pragma unroll
        for (int kk = 0; kk < 2; kk++) {
            f16x8 af[4], bfr[4];
#pragma unroll
            for (int mi = 0; mi < 4; mi++) {
                int r = (wid >> 1) * 64 + mi * 16 + fr;
                af[mi] = *(const f16x8*)(As + r * 64 + ((((kk << 2) + g) ^ (r & 7)) << 3));
            }
#pragma unroll
            for (int ni = 0; ni < 4; ni++) {
                int r = (wid & 1) * 64 + ni * 16 + fr;
                bfr[ni] = *(const f16x8*)(Bs + r * 64 + ((((kk << 2) + g) ^ (r & 7)) << 3));
            }
#pragma unroll
            for (int mi = 0; mi < 4; mi++)
#pragma unroll
                for (int ni = 0; ni < 4; ni++)
                    acc[mi][ni] = __builtin_amdgcn_mfma_f32_16x16x32_f16(af[mi], bfr[ni], acc[mi][ni], 0, 0, 0);
        }
        __syncthreads();
    }

#pragma unroll
    for (int mi = 0; mi < 4; mi++) {
        int row = rowA0 + (wid >> 1) * 64 + mi * 16 + g * 4;
#pragma unroll
        for (int ni = 0; ni < 4; ni++) {
            int col = colB0 + (wid & 1) * 64 + ni * 16 + fr;
#pragma unroll
            for (int r = 0; r < 4; r++)
                C[(size_t)(row + r) * N + col] = acc[mi][ni][r];
        }
    }
}

// ---------- RMS/L2 norm + partial RoPE; fp16 outputs ----------
__global__ __launch_bounds__(256) void k_norm_rope(float* __restrict__ qkv,
                                                   const float* __restrict__ q_scale,
                                                   const float* __restrict__ k_scale,
                                                   unsigned short* __restrict__ Qh,
                                                   unsigned short* __restrict__ Kh) {
    __shared__ float Y[256];
    __shared__ float red[4];
    int blk = blockIdx.x;
    int bt = blk >> 4, slot = blk & 15;
    int b = bt >> 11, t = bt & 2047;
    int h = threadIdx.x;
    int lane = h & 63, wid = h >> 6;

    float x = qkv[(size_t)bt * 4096 + slot * 256 + h];
    float v = x * x;
#pragma unroll
    for (int m = 1; m < 64; m <<= 1) v += __shfl_xor(v, m);
    if (lane == 0) red[wid] = v;
    __syncthreads();
    float ss = red[0] + red[1] + red[2] + red[3];

    float y;
    if (slot < 12) {
        float fac = rsqrtf(ss * (1.0f / 256.0f) + 1e-6f);
        const float* sc = (slot < 8) ? q_scale : k_scale;
        y = x * fac * (1.0f + sc[h]);
    } else {
        float fac = rsqrtf(ss + 1e-6f);
        y = x * fac;
    }
    Y[h] = y;
    __syncthreads();

    if (slot < 12) {
        float out;
        int hm = h & 127;
        if (hm < 64) {
            float inv = exp2f(-(float)hm * 0.10381025296522993f); // log2(10000)/128
            float fr = (float)t * inv;
            float s = sinf(fr), c = cosf(fr);
            float y1 = Y[hm], y2 = Y[128 + hm];
            out = (h < 128) ? (y1 * c - y2 * s) : (y2 * c + y1 * s);
        } else {
            out = y;
        }
        unsigned short hv = f2h(out);
        if (slot < 8)
            Qh[((size_t)(b * 8 + slot) * 2048 + t) * 256 + h] = hv;
        else
            Kh[((size_t)(b * 4 + (slot - 8)) * 2048 + t) * 256 + h] = hv;
    } else {
        qkv[(size_t)bt * 4096 + slot * 256 + h] = y;   // normalized v, f32 in-place
    }
}

// ---------- causal flash attention v7: 128 q-rows/block, waves own rows, dbuf ----------
// grid 256 x 512 thr (8 waves). id = qt(4b)|npar(1b)|bkv(3b): id%8 = bkv -> XCD-affine.
// Wave w owns q-rows qt*128 + w*16 .. +15 COMPLETELY (all 64 keys per tile; 4 key-
// subtiles) -> no c2 split, no merge. KV staged once per 128 q-rows: per-CU inbound
// traffic HALVED vs 64q blocks (the r8/r10 ~23GB/s/CU wall). nkt = 2qt+2 (imbalanced;
// straggler qt=15 flagged -> split-k next if tail shows). Double-buffer: LDS = 128KB.
__global__ __launch_bounds__(512, 2) void k_attn(const unsigned short* __restrict__ Qhg,
                                                 const unsigned short* __restrict__ Khg,
                                                 const unsigned short* __restrict__ Vtg,
                                                 unsigned short* __restrict__ attn) {
    __shared__ __align__(16) unsigned short KV[65536];   // 128KB
    unsigned short* Ks = KV;             // [buf][64key x 256d], chunk^=(key&7)
    unsigned short* Vs = KV + 32768;     // [buf][256d x 64key], chunk^=(d&7)

    int id = blockIdx.x;
    int bkv = id & 7;
    int npar = (id >> 3) & 1;
    int qt = id >> 4;                    // 0..15
    int b = bkv >> 2, kv = bkv & 3;
    int n = kv * 2 + npar;
    int bn = b * 8 + n;
    int nkt = 2 * qt + 2;

    int tid = threadIdx.x, lane = tid & 63, wid = tid >> 6;
    int g = lane >> 4, fr = lane & 15;
    int g4 = g * 4, s7 = fr & 7;
    int q0 = qt * 128 + wid * 16;

    const unsigned short* Kh = Khg + (size_t)bkv * 2048 * 256;
    const unsigned short* Vh = Vtg + (size_t)bkv * 256 * 2048;
    const unsigned short* Qb = Qhg + (size_t)bn * 2048 * 256;

    // staging bases: 64KB/512thr = 8 gload16/thread (4 K + 4 V)
    const unsigned short* kb[4];
    const unsigned short* vb[4];
    int sd[4];
#pragma unroll
    for (int t2 = 0; t2 < 4; t2++) {
        int c_ = t2 * 512 + tid;
        int r = c_ >> 5, c = (c_ & 31) ^ (r & 7);
        kb[t2] = Kh + (size_t)r * 256 + c * 8;
        int d = c_ >> 3, cv = (c_ & 7) ^ (d & 7);
        vb[t2] = Vh + (size_t)d * 2048 + cv * 8;
        sd[t2] = c_ * 8;
    }

    int krb[4], vsl[4];
#pragma unroll
    for (int t16 = 0; t16 < 4; t16++) {
        krb[t16] = (t16 * 16 + fr) * 256;
        vsl[t16] = (((t16 * 2 + (g >> 1)) ^ s7) << 3) + (g & 1) * 4;
    }

    const unsigned short* qrow = Qb + (size_t)(q0 + fr) * 256;
    f16x8 aq[8];
#pragma unroll
    for (int kk = 0; kk < 8; kk++) aq[kk] = *(const f16x8*)(qrow + kk * 32 + g * 8);

    f32x4 zero4 = {0.f, 0.f, 0.f, 0.f};
    f32x4 o[16];
#pragma unroll
    for (int i2 = 0; i2 < 16; i2++) o[i2] = zero4;
    float m_run = -1e30f;   // per-lane for q = q0 + fr
    float l_run = 0.f;      // per-lane partial (reduced over g at end)

    auto STAGE = [&](int bufi, int kt2) {
#pragma unroll
        for (int t2 = 0; t2 < 4; t2++) {
            gload16(kb[t2] + (size_t)kt2 * 16384, Ks + bufi * 16384 + sd[t2]);
            gload16(vb[t2] + kt2 * 64, Vs + bufi * 16384 + sd[t2]);
        }
    };

    STAGE(0, 0);
    __syncthreads();

    for (int kt = 0; kt < nkt; kt++) {
        int cur = kt & 1;
        if (kt + 1 < nkt) STAGE(cur ^ 1, kt + 1);   // prefetch overlaps compute

        const unsigned short* KH = Ks + cur * 16384;
        const unsigned short* VC = Vs + cur * 16384;
        int k0 = kt * 64;

        // S^T = K Q^T over all 64 keys: 4 independent acc chains
        f32x4 se[4] = {zero4, zero4, zero4, zero4};
        __builtin_amdgcn_s_setprio(1);
#pragma unroll
        for (int kk = 0; kk < 8; kk++) {
#pragma unroll
            for (int t16 = 0; t16 < 4; t16++) {
                f16x8 bk = *(const f16x8*)(KH + krb[t16] + ((((kk << 2) + g) ^ s7) << 3));
                se[t16] = __builtin_amdgcn_mfma_f32_16x16x32_f16(bk, aq[kk], se[t16], 0, 0, 0);
            }
        }
        __builtin_amdgcn_s_setprio(0);

        // softcap 50*tanh(s/50) = 50 - 100/(1+e^{0.04s}), causal mask; lane-local rows
        int qg = q0 + fr;
        float p4[4][4];
        float ml = -1e30f;
#pragma unroll
        for (int t16 = 0; t16 < 4; t16++)
#pragma unroll
            for (int r = 0; r < 4; r++) {
                float s = se[t16][r];
                float e = __expf(0.04f * s);
                s = 50.f - 100.f * __builtin_amdgcn_rcpf(1.f + e);
                int key = k0 + t16 * 16 + g4 + r;
                if (key > qg) s = -1e9f;
                p4[t16][r] = s;
                ml = fmaxf(ml, s);
            }
        ml = fmaxf(ml, __shfl_xor(ml, 16));
        ml = fmaxf(ml, __shfl_xor(ml, 32));

        // defer-max (THR=8)
        if (__any(ml > m_run + 8.f)) {
            float mnew = fmaxf(m_run, ml);
            float swl = __expf(m_run - mnew);
            m_run = mnew;
            l_run *= swl;
            float swr[4];
#pragma unroll
            for (int r = 0; r < 4; r++) swr[r] = __shfl(swl, g4 + r);
#pragma unroll
            for (int nt = 0; nt < 16; nt++)
#pragma unroll
                for (int r = 0; r < 4; r++) o[nt][r] *= swr[r];
        }

        // P = exp(s - m_run), fp16 A-frags for K=16 PV
        f16x4 pf[4];
#pragma unroll
        for (int t16 = 0; t16 < 4; t16++)
#pragma unroll
            for (int r = 0; r < 4; r++) {
                float p = __expf(p4[t16][r] - m_run);
                l_run += p;
                pf[t16][r] = (_Float16)p;
            }

        // O += P V : per nt, 4 K=16 MFMAs (one per key-subtile)
        __builtin_amdgcn_s_setprio(1);
#pragma unroll
        for (int nt = 0; nt < 16; nt++) {
            int dbase = (nt * 16 + fr) * 64;
#pragma unroll
            for (int t16 = 0; t16 < 4; t16++) {
                f16x4 bv = *(const f16x4*)(VC + dbase + vsl[t16]);
                o[nt] = MFMA_K16(pf[t16], bv, o[nt]);
            }
        }
        __builtin_amdgcn_s_setprio(0);
        __syncthreads();   // drains prefetch vmcnt; next iter flips buffers
    }

    // finalize: reduce l over the 4 g-lanes per row, write output
    float l2 = l_run + __shfl_xor(l_run, 16);
    l2 += __shfl_xor(l2, 32);
    float li = __builtin_amdgcn_rcpf(fmaxf(l2, 1e-30f));
    float lrow[4];
#pragma unroll
    for (int r = 0; r < 4; r++) lrow[r] = __shfl(li, g4 + r);
#pragma unroll
    for (int nt = 0; nt < 16; nt++)
#pragma unroll
        for (int r = 0; r < 4; r++) {
            int qr = q0 + g4 + r;
            attn[(size_t)(b * 2048 + qr) * 2048 + n * 256 + nt * 16 + fr] = f2h(o[nt][r] * lrow[r]);
        }
}

extern "C" void kernel_launch(void* const* d_in, const int* in_sizes, int n_in,
                              void* d_out, int out_size, void* d_ws, size_t ws_size,
                              hipStream_t stream) {
    const float* x       = (const float*)d_in[0];
    // d_in[1] = attention_mask: deterministically causal -> applied analytically
    const float* Wq      = (const float*)d_in[2];
    const float* Wk      = (const float*)d_in[3];
    const float* Wv      = (const float*)d_in[4];
    const float* Wo      = (const float*)d_in[5];
    const float* q_scale = (const float*)d_in[6];
    const float* k_scale = (const float*)d_in[7];
    float* out = (float*)d_out;
    char* ws = (char*)d_ws;

    // workspace (peak 104 MB):
    //   [0,16M):   xh fp16 -> dead after GEMM1 -> Qh fp16 [16][2048][256]
    //   [16M,32M): WT fp16 (qkv weights B^T) -> dead after GEMM1 -> Kh[16,24M) Vt[24,32M)
    //   [32M,40M): WoT fp16
    //   [40M,104M): qkv f32 4096x4096 -> dead after V-transpose -> attnb fp16 [40,56M)
    const size_t MB = 1024 * 1024;
    unsigned short* xh    = (unsigned short*)ws;
    unsigned short* Qh    = (unsigned short*)ws;
    unsigned short* WT    = (unsigned short*)(ws + 16 * MB);
    unsigned short* Kh    = (unsigned short*)(ws + 16 * MB);
    unsigned short* Vt    = (unsigned short*)(ws + 24 * MB);
    unsigned short* WoT   = (unsigned short*)(ws + 32 * MB);
    float*          qkv   = (float*)(ws + 40 * MB);
    unsigned short* attnb = (unsigned short*)(ws + 40 * MB);

    dim3 tb(32, 8);
    k_prep<<<dim3(8, 64, 25), tb, 0, stream>>>(x, Wq, Wk, Wv, Wo, xh, WT, WoT);

    k_gemm256<<<dim3(256), dim3(512), 0, stream>>>(xh, WT, qkv, 4096, 4096, 2048, 16);
    k_norm_rope<<<dim3(65536), dim3(256), 0, stream>>>(qkv, q_scale, k_scale, Qh, Kh);
    for (int b = 0; b < 2; b++)
        k_transpose_cvt<<<dim3(8, 64, 4), tb, 0, stream>>>(qkv + (size_t)b * 2048 * 4096 + 3072,
                                                           Vt + (size_t)b * 4 * 256 * 2048,
                                                           4096, 2048, 256L, 524288L);
    k_attn<<<dim3(256), dim3(512), 0, stream>>>(Qh, Kh, Vt, attnb);

    k_gemm_f16<<<dim3(16, 32), dim3(256), 0, stream>>>(attnb, WoT, out, 4096, 2048, 2048);
}

// Round 12
// 297.497 us; speedup vs baseline: 1.0399x; 1.0399x over previous
//
#include <hip/hip_runtime.h>

#define AS1 __attribute__((address_space(1)))
#define AS3 __attribute__((address_space(3)))

typedef __attribute__((ext_vector_type(8))) _Float16 f16x8;
typedef __attribute__((ext_vector_type(4))) _Float16 f16x4;
typedef __attribute__((ext_vector_type(4))) float f32x4;

#define MFMA_K16(a, b, c) __builtin_amdgcn_mfma_f32_16x16x16f16(a, b, c, 0, 0, 0)
#define MFMA_K32(a, b, c) __builtin_amdgcn_mfma_f32_16x16x32_f16(a, b, c, 0, 0, 0)

__device__ __forceinline__ unsigned short f2h(float f) {
    union { _Float16 h; unsigned short u; } v; v.h = (_Float16)f; return v.u;
}

__device__ __forceinline__ void gload16(const void* g, void* l) {
    __builtin_amdgcn_global_load_lds((const AS1 unsigned int*)g, (AS3 unsigned int*)l, 16, 0, 0);
}

#define GBAR() __builtin_amdgcn_s_barrier()
#define VM4()  asm volatile("s_waitcnt vmcnt(4)" ::: "memory")
#define VM0()  asm volatile("s_waitcnt vmcnt(0)" ::: "memory")

// ---------- fused prep: x->fp16 cvt (z=24), Wq/Wk/Wv transposes (z<16), Wo transpose (z 16..23) ----------
__global__ __launch_bounds__(256) void k_prep(const float* __restrict__ x,
                                              const float* __restrict__ Wq,
                                              const float* __restrict__ Wk,
                                              const float* __restrict__ Wv,
                                              const float* __restrict__ Wo,
                                              unsigned short* __restrict__ xh,
                                              unsigned short* __restrict__ WT,
                                              unsigned short* __restrict__ WoT) {
    int z = blockIdx.z;
    if (z == 24) {
        int blk = blockIdx.y * 8 + blockIdx.x;
        int t = threadIdx.y * 32 + threadIdx.x;
        const float4* s4 = (const float4*)x;
        ushort4* d4 = (ushort4*)xh;
        int base = blk * 4096 + t;
#pragma unroll
        for (int i = 0; i < 16; i++) {
            float4 v = s4[base + i * 256];
            ushort4 u;
            u.x = f2h(v.x); u.y = f2h(v.y); u.z = f2h(v.z); u.w = f2h(v.w);
            d4[base + i * 256] = u;
        }
        return;
    }
    const float* src; unsigned short* dst;
    int ld_src, c0, r0;
    if (z < 16) {
        if (z < 8)       { src = Wq + (size_t)z * 524288;        dst = WT + (size_t)z * 524288; }
        else if (z < 12) { src = Wk + (size_t)(z - 8) * 524288;  dst = WT + (size_t)2048 * 2048 + (size_t)(z - 8) * 524288; }
        else             { src = Wv + (size_t)(z - 12) * 524288; dst = WT + (size_t)3072 * 2048 + (size_t)(z - 12) * 524288; }
        ld_src = 256;
        c0 = blockIdx.x * 32; r0 = blockIdx.y * 32;
    } else {
        src = Wo; dst = WoT; ld_src = 2048;
        c0 = ((z - 16) * 8 + blockIdx.x) * 32; r0 = blockIdx.y * 32;
    }
    __shared__ float tile[32][33];
    int tx = threadIdx.x, ty = threadIdx.y;
#pragma unroll
    for (int i = 0; i < 4; i++)
        tile[ty + i * 8][tx] = src[(size_t)(r0 + ty + i * 8) * ld_src + c0 + tx];
    __syncthreads();
#pragma unroll
    for (int i = 0; i < 4; i++)
        dst[(size_t)(c0 + ty + i * 8) * 2048 + r0 + tx] = f2h(tile[tx][ty + i * 8]);
}

// ---------- tiled transpose + convert (for V) ----------
__global__ __launch_bounds__(256) void k_transpose_cvt(const float* __restrict__ src,
                                                       unsigned short* __restrict__ dst,
                                                       int ld_src, int ld_dst,
                                                       long zs_src, long zs_dst) {
    __shared__ float tile[32][33];
    long sb = (long)blockIdx.z * zs_src;
    long db = (long)blockIdx.z * zs_dst;
    int c0 = blockIdx.x * 32, r0 = blockIdx.y * 32;
    int tx = threadIdx.x, ty = threadIdx.y;
#pragma unroll
    for (int i = 0; i < 4; i++)
        tile[ty + i * 8][tx] = src[sb + (long)(r0 + ty + i * 8) * ld_src + c0 + tx];
    __syncthreads();
#pragma unroll
    for (int i = 0; i < 4; i++)
        dst[db + (long)(c0 + ty + i * 8) * ld_dst + r0 + tx] = f2h(tile[tx][ty + i * 8]);
}

// ======== 256x256 8-phase fp16 GEMM (T2+T3+T4+T5) ========
template<int BUF, int MIH>
__device__ __forceinline__ void rdA(const unsigned short* SA, int wm, int fr, int g,
                                    f16x8 (&af)[4][2]) {
#pragma unroll
    for (int m = 0; m < 4; m++)
#pragma unroll
        for (int kk = 0; kk < 2; kk++) {
            int pos = wm * 64 + m * 16 + fr;
            af[m][kk] = *(const f16x8*)(SA + BUF * 16384 + MIH * 8192 + pos * 64 +
                                        (((kk * 4 + g) ^ (fr & 7)) << 3));
        }
}

template<int BUF, int NIH>
__device__ __forceinline__ void rdB(const unsigned short* SB, int wn, int fr, int g,
                                    f16x8 (&bf)[2][2]) {
#pragma unroll
    for (int ni2 = 0; ni2 < 2; ni2++)
#pragma unroll
        for (int kk = 0; kk < 2; kk++) {
            int pos = wn * 32 + ni2 * 16 + fr;
            bf[ni2][kk] = *(const f16x8*)(SB + BUF * 16384 + NIH * 8192 + pos * 64 +
                                          (((kk * 4 + g) ^ (fr & 7)) << 3));
        }
}

template<int MIH, int NIH>
__device__ __forceinline__ void mm16(f16x8 (&af)[4][2], f16x8 (&bf)[2][2], f32x4 (&acc)[8][4]) {
    __builtin_amdgcn_s_setprio(1);
#pragma unroll
    for (int m = 0; m < 4; m++)
#pragma unroll
        for (int ni2 = 0; ni2 < 2; ni2++)
#pragma unroll
            for (int kk = 0; kk < 2; kk++)
                acc[MIH * 4 + m][NIH * 2 + ni2] = MFMA_K32(af[m][kk], bf[ni2][kk],
                                                           acc[MIH * 4 + m][NIH * 2 + ni2]);
    __builtin_amdgcn_s_setprio(0);
}

__global__ __launch_bounds__(512, 1) void k_gemm256(const unsigned short* __restrict__ A,
                                                    const unsigned short* __restrict__ Bt,
                                                    float* __restrict__ C,
                                                    int M, int N, int K, int nbx) {
    __shared__ __align__(16) unsigned short sm[65536];
    unsigned short* SA = sm;
    unsigned short* SB = sm + 32768;

    int tid = threadIdx.x, lane = tid & 63, wid = tid >> 6;
    int g = lane >> 4, fr = lane & 15;
    int wm = wid >> 2, wn = wid & 3;

    int bid = blockIdx.x;
    int sid = (bid & 7) * ((int)gridDim.x >> 3) + (bid >> 3);
    int by = sid / nbx, bx = sid % nbx;
    int rowA0 = by * 256, colB0 = bx * 256;

    f32x4 acc[8][4];
#pragma unroll
    for (int mi = 0; mi < 8; mi++)
#pragma unroll
        for (int ni = 0; ni < 4; ni++) acc[mi][ni] = (f32x4){0.f, 0.f, 0.f, 0.f};

    auto stA = [&](int buf, int h, int kt) {
#pragma unroll
        for (int t = 0; t < 2; t++) {
            int i = t * 512 + tid;
            int pos = i >> 3;
            int grow = rowA0 + ((pos >> 6) << 7) + h * 64 + (pos & 63);
            int cg = (i & 7) ^ (pos & 7);
            gload16(A + (size_t)grow * K + kt * 64 + cg * 8,
                    SA + buf * 16384 + h * 8192 + pos * 64 + (i & 7) * 8);
        }
    };
    auto stB = [&](int buf, int h, int kt) {
#pragma unroll
        for (int t = 0; t < 2; t++) {
            int i = t * 512 + tid;
            int pos = i >> 3;
            int gcol = colB0 + ((pos >> 5) << 6) + h * 32 + (pos & 31);
            int cg = (i & 7) ^ (pos & 7);
            gload16(Bt + (size_t)gcol * K + kt * 64 + cg * 8,
                    SB + buf * 16384 + h * 8192 + pos * 64 + (i & 7) * 8);
        }
    };

    int nT = K >> 6;
    stA(0, 0, 0); stB(0, 0, 0); stA(0, 1, 0); stB(0, 1, 0);
    stA(1, 0, 1); stB(1, 0, 1);
    VM4();
    GBAR();

    f16x8 af[4][2], bf[2][2];
    int nIt = nT >> 1;
    for (int it = 0; it < nIt; it++) {
        int T = it * 2;
        bool s36 = (T + 2 < nT), s78 = (T + 3 < nT);
        rdA<0, 0>(SA, wm, fr, g, af); rdB<0, 0>(SB, wn, fr, g, bf);
        stA(1, 1, T + 1);
        GBAR(); mm16<0, 0>(af, bf, acc); GBAR();
        rdB<0, 1>(SB, wn, fr, g, bf);
        stB(1, 1, T + 1);
        GBAR(); mm16<0, 1>(af, bf, acc); GBAR();
        rdA<0, 1>(SA, wm, fr, g, af); rdB<0, 0>(SB, wn, fr, g, bf);
        if (s36) stA(0, 0, T + 2);
        GBAR(); mm16<1, 0>(af, bf, acc); GBAR();
        rdB<0, 1>(SB, wn, fr, g, bf);
        if (s36) { stB(0, 0, T + 2); VM4(); } else { VM0(); }
        GBAR(); mm16<1, 1>(af, bf, acc); GBAR();
        rdA<1, 0>(SA, wm, fr, g, af); rdB<1, 0>(SB, wn, fr, g, bf);
        if (s36) stA(0, 1, T + 2);
        GBAR(); mm16<0, 0>(af, bf, acc); GBAR();
        rdB<1, 1>(SB, wn, fr, g, bf);
        if (s36) stB(0, 1, T + 2);
        GBAR(); mm16<0, 1>(af, bf, acc); GBAR();
        rdA<1, 1>(SA, wm, fr, g, af); rdB<1, 0>(SB, wn, fr, g, bf);
        if (s78) stA(1, 0, T + 3);
        GBAR(); mm16<1, 0>(af, bf, acc); GBAR();
        rdB<1, 1>(SB, wn, fr, g, bf);
        if (s78) { stB(1, 0, T + 3); VM4(); } else { VM0(); }
        GBAR(); mm16<1, 1>(af, bf, acc); GBAR();
    }

#pragma unroll
    for (int mi = 0; mi < 8; mi++) {
        int row = rowA0 + wm * 128 + mi * 16 + g * 4;
#pragma unroll
        for (int ni = 0; ni < 4; ni++) {
            int col = colB0 + wn * 64 + ni * 16 + fr;
#pragma unroll
            for (int r = 0; r < 4; r++)
                C[(size_t)(row + r) * N + col] = acc[mi][ni][r];
        }
    }
}

// ---------- fp16 GEMM (out-proj): 128x128 tile ----------
__global__ __launch_bounds__(256) void k_gemm_f16(const unsigned short* __restrict__ A,
                                                  const unsigned short* __restrict__ Bt,
                                                  float* __restrict__ C,
                                                  int M, int N, int K) {
    __shared__ unsigned short As[128 * 64];
    __shared__ unsigned short Bs[128 * 64];
    int tid = threadIdx.x;
    int lane = tid & 63, wid = tid >> 6;
    int g = lane >> 4, fr = lane & 15;
    int rowA0 = blockIdx.y * 128;
    int colB0 = blockIdx.x * 128;

    f32x4 zero = {0.f, 0.f, 0.f, 0.f};
    f32x4 acc[4][4];
#pragma unroll
    for (int mi = 0; mi < 4; mi++)
#pragma unroll
        for (int ni = 0; ni < 4; ni++) acc[mi][ni] = zero;

    const unsigned short* ag[4];
    const unsigned short* bg[4];
#pragma unroll
    for (int j = 0; j < 4; j++) {
        int id = j * 256 + tid;
        int r = id >> 3;
        int c = (id & 7) ^ (r & 7);
        ag[j] = A + (size_t)(rowA0 + r) * K + c * 8;
        bg[j] = Bt + (size_t)(colB0 + r) * K + c * 8;
    }

    int nK = K >> 6;
    for (int kt = 0; kt < nK; kt++) {
#pragma unroll
        for (int j = 0; j < 4; j++) {
            int id = j * 256 + tid;
            gload16(ag[j], As + id * 8);
            gload16(bg[j], Bs + id * 8);
            ag[j] += 64; bg[j] += 64;
        }
        __syncthreads();
#pragma unroll
        for (int kk = 0; kk < 2; kk++) {
            f16x8 af[4], bfr[4];
#pragma unroll
            for (int mi = 0; mi < 4; mi++) {
                int r = (wid >> 1) * 64 + mi * 16 + fr;
                af[mi] = *(const f16x8*)(As + r * 64 + ((((kk << 2) + g) ^ (r & 7)) << 3));
            }
#pragma unroll
            for (int ni = 0; ni < 4; ni++) {
                int r = (wid & 1) * 64 + ni * 16 + fr;
                bfr[ni] = *(const f16x8*)(Bs + r * 64 + ((((kk << 2) + g) ^ (r & 7)) << 3));
            }
#pragma unroll
            for (int mi = 0; mi < 4; mi++)
#pragma unroll
                for (int ni = 0; ni < 4; ni++)
                    acc[mi][ni] = MFMA_K32(af[mi], bfr[ni], acc[mi][ni]);
        }
        __syncthreads();
    }

#pragma unroll
    for (int mi = 0; mi < 4; mi++) {
        int row = rowA0 + (wid >> 1) * 64 + mi * 16 + g * 4;
#pragma unroll
        for (int ni = 0; ni < 4; ni++) {
            int col = colB0 + (wid & 1) * 64 + ni * 16 + fr;
#pragma unroll
            for (int r = 0; r < 4; r++)
                C[(size_t)(row + r) * N + col] = acc[mi][ni][r];
        }
    }
}

// ---------- RMS/L2 norm + partial RoPE; fp16 outputs ----------
__global__ __launch_bounds__(256) void k_norm_rope(float* __restrict__ qkv,
                                                   const float* __restrict__ q_scale,
                                                   const float* __restrict__ k_scale,
                                                   unsigned short* __restrict__ Qh,
                                                   unsigned short* __restrict__ Kh) {
    __shared__ float Y[256];
    __shared__ float red[4];
    int blk = blockIdx.x;
    int bt = blk >> 4, slot = blk & 15;
    int b = bt >> 11, t = bt & 2047;
    int h = threadIdx.x;
    int lane = h & 63, wid = h >> 6;

    float x = qkv[(size_t)bt * 4096 + slot * 256 + h];
    float v = x * x;
#pragma unroll
    for (int m = 1; m < 64; m <<= 1) v += __shfl_xor(v, m);
    if (lane == 0) red[wid] = v;
    __syncthreads();
    float ss = red[0] + red[1] + red[2] + red[3];

    float y;
    if (slot < 12) {
        float fac = rsqrtf(ss * (1.0f / 256.0f) + 1e-6f);
        const float* sc = (slot < 8) ? q_scale : k_scale;
        y = x * fac * (1.0f + sc[h]);
    } else {
        float fac = rsqrtf(ss + 1e-6f);
        y = x * fac;
    }
    Y[h] = y;
    __syncthreads();

    if (slot < 12) {
        float out;
        int hm = h & 127;
        if (hm < 64) {
            float inv = exp2f(-(float)hm * 0.10381025296522993f); // log2(10000)/128
            float fr = (float)t * inv;
            float s = sinf(fr), c = cosf(fr);
            float y1 = Y[hm], y2 = Y[128 + hm];
            out = (h < 128) ? (y1 * c - y2 * s) : (y2 * c + y1 * s);
        } else {
            out = y;
        }
        unsigned short hv = f2h(out);
        if (slot < 8)
            Qh[((size_t)(b * 8 + slot) * 2048 + t) * 256 + h] = hv;
        else
            Kh[((size_t)(b * 4 + (slot - 8)) * 2048 + t) * 256 + h] = hv;
    } else {
        qkv[(size_t)bt * 4096 + slot * 256 + h] = y;   // normalized v, f32 in-place
    }
}

// ---------- causal flash attention v8: 32q/wave B-frag reuse, 4-wave blocks ----------
// grid 512 x 256 thr (4 waves). id = half(1b)|pair(4b)|npar(1b)|bkv(3b): id%8 = bkv
// (XCD-affine); blocks id and id+256 get complementary tiles {j, 31-j} -> with round-
// robin dispatch each CU hosts 2 co-resident blocks totalling 33 iters (balanced) and
// they mutually hide staging (single K/V buffer, 65KB LDS -> 2 blocks/CU).
// Waves: rg=wid>>1 (32 q-rows), kh=wid&1 (32-key half). Each wave computes 32q x 32k:
// every K/V B-fragment read from LDS feeds TWO MFMAs (q-subtiles) -> LDS read traffic
// per unit of work HALVED vs 16q/wave (the r8..r11 LDS-bandwidth wall).
// One kh0<->kh1 merge at tile end reuses the dead K/V LDS as the 64KB X overlay.
__global__ __launch_bounds__(256, 2) void k_attn(const unsigned short* __restrict__ Qhg,
                                                 const unsigned short* __restrict__ Khg,
                                                 const unsigned short* __restrict__ Vtg,
                                                 unsigned short* __restrict__ attn) {
    __shared__ __align__(16) char smem[66560];
    unsigned short* Ks = (unsigned short*)smem;            // [64key][32chunk] src-swz ^(key&7)
    unsigned short* Vs = (unsigned short*)(smem + 32768);  // [256d][8chunk]  src-swz ^(d&7)
    float* X  = (float*)smem;                              // merge overlay [2rg][32q][256d] f32
    float* ML = (float*)(smem + 65536);                    // [2rg][2kh][2qsub][16][2]

    int id = blockIdx.x;
    int bkv = id & 7;
    int npar = (id >> 3) & 1;
    int pairidx = (id >> 4) & 15;
    int half = id >> 8;
    int b = bkv >> 2, kv = bkv & 3;
    int n = kv * 2 + npar;
    int bn = b * 8 + n;
    int j = half ? 31 - pairidx : pairidx;
    int nkt = j + 1;

    int tid = threadIdx.x, lane = tid & 63, wid = tid >> 6;
    int rg = wid >> 1, kh = wid & 1;
    int g = lane >> 4, fr = lane & 15;
    int g4 = g * 4, s7 = fr & 7;
    int q0 = j * 64 + rg * 32;

    const unsigned short* Kh = Khg + (size_t)bkv * 2048 * 256;
    const unsigned short* Vh = Vtg + (size_t)bkv * 256 * 2048;
    const unsigned short* Qb = Qhg + (size_t)bn * 2048 * 256;

    // Q B-frags for both 16-row subtiles (held in regs all 33 iters): 64 VGPR
    f16x8 bq[2][8];
#pragma unroll
    for (int qsub = 0; qsub < 2; qsub++) {
        const unsigned short* qrow = Qb + (size_t)(q0 + qsub * 16 + fr) * 256;
#pragma unroll
        for (int kk = 0; kk < 8; kk++)
            bq[qsub][kk] = *(const f16x8*)(qrow + kk * 32 + g * 8);
    }

    // stage source offsets (int, relative; +k0-scaled term per iter)
    int koff[8], voff[8];
#pragma unroll
    for (int t2 = 0; t2 < 8; t2++) {
        int c_ = t2 * 256 + tid;
        int key = c_ >> 5, ck = (c_ & 31) ^ (key & 7);
        koff[t2] = key * 256 + ck * 8;
        int d = c_ >> 3, cv = (c_ & 7) ^ (d & 7);
        voff[t2] = d * 2048 + cv * 8;
    }

    int krb[2];
#pragma unroll
    for (int t16 = 0; t16 < 2; t16++) krb[t16] = (kh * 32 + t16 * 16 + fr) * 256;
    int vsl[2];
#pragma unroll
    for (int t16 = 0; t16 < 2; t16++)
        vsl[t16] = (((kh * 4 + t16 * 2 + (g >> 1)) ^ s7) << 3) + (g & 1) * 4;

    f32x4 zero4 = {0.f, 0.f, 0.f, 0.f};
    f32x4 o[2][16];
#pragma unroll
    for (int qsub = 0; qsub < 2; qsub++)
#pragma unroll
        for (int i2 = 0; i2 < 16; i2++) o[qsub][i2] = zero4;
    float m_run[2] = {-1e30f, -1e30f};
    float l_run[2] = {0.f, 0.f};

    for (int kt = 0; kt < nkt; kt++) {
        int k0 = kt * 64;
        // stage K 32KB + V 32KB (16 gload16/thread); sync drains vmcnt
#pragma unroll
        for (int t2 = 0; t2 < 8; t2++) {
            int c_ = t2 * 256 + tid;
            gload16(Kh + (size_t)k0 * 256 + koff[t2], Ks + c_ * 8);
            gload16(Vh + k0 + voff[t2], Vs + c_ * 8);
        }
        __syncthreads();

        // S^T = K Q^T: 16 B-frag reads -> 32 MFMA (each K-frag used by both q-subtiles)
        f32x4 se[2][2] = {{zero4, zero4}, {zero4, zero4}};
        __builtin_amdgcn_s_setprio(1);
#pragma unroll
        for (int kk = 0; kk < 8; kk++) {
            int co = ((((kk << 2) + g) ^ s7) << 3);
            f16x8 bk0 = *(const f16x8*)(Ks + krb[0] + co);
            f16x8 bk1 = *(const f16x8*)(Ks + krb[1] + co);
            se[0][0] = MFMA_K32(bk0, bq[0][kk], se[0][0]);
            se[1][0] = MFMA_K32(bk0, bq[1][kk], se[1][0]);
            se[0][1] = MFMA_K32(bk1, bq[0][kk], se[0][1]);
            se[1][1] = MFMA_K32(bk1, bq[1][kk], se[1][1]);
        }
        __builtin_amdgcn_s_setprio(0);

        // softcap 50*tanh(s/50) = 50 - 100/(1+e^{0.04s}), causal mask
        float p4[2][2][4];
        float ml2[2] = {-1e30f, -1e30f};
#pragma unroll
        for (int qsub = 0; qsub < 2; qsub++) {
            int qg = q0 + qsub * 16 + fr;
#pragma unroll
            for (int t16 = 0; t16 < 2; t16++)
#pragma unroll
                for (int r = 0; r < 4; r++) {
                    float s = se[qsub][t16][r];
                    float e = __expf(0.04f * s);
                    s = 50.f - 100.f * __builtin_amdgcn_rcpf(1.f + e);
                    int key = k0 + kh * 32 + t16 * 16 + g4 + r;
                    if (key > qg) s = -1e9f;
                    p4[qsub][t16][r] = s;
                    ml2[qsub] = fmaxf(ml2[qsub], s);
                }
        }
#pragma unroll
        for (int qsub = 0; qsub < 2; qsub++) {
            ml2[qsub] = fmaxf(ml2[qsub], __shfl_xor(ml2[qsub], 16));
            ml2[qsub] = fmaxf(ml2[qsub], __shfl_xor(ml2[qsub], 32));
        }

        // defer-max (THR=8)
        int needs = (ml2[0] > m_run[0] + 8.f) || (ml2[1] > m_run[1] + 8.f);
        if (__any(needs)) {
#pragma unroll
            for (int qsub = 0; qsub < 2; qsub++) {
                float mnew = fmaxf(m_run[qsub], ml2[qsub]);
                float swl = __expf(m_run[qsub] - mnew);
                m_run[qsub] = mnew;
                l_run[qsub] *= swl;
                float swr[4];
#pragma unroll
                for (int r = 0; r < 4; r++) swr[r] = __shfl(swl, g4 + r);
#pragma unroll
                for (int nt = 0; nt < 16; nt++)
#pragma unroll
                    for (int r = 0; r < 4; r++) o[qsub][nt][r] *= swr[r];
            }
        }

        // P = exp(s - m) -> fp16 A-frags (zero data movement)
        f16x4 pf[2][2];
#pragma unroll
        for (int qsub = 0; qsub < 2; qsub++)
#pragma unroll
            for (int t16 = 0; t16 < 2; t16++)
#pragma unroll
                for (int r = 0; r < 4; r++) {
                    float p = __expf(p4[qsub][t16][r] - m_run[qsub]);
                    l_run[qsub] += p;
                    pf[qsub][t16][r] = (_Float16)p;
                }

        // O += P V: 32 V-frag reads -> 64 MFMA (each V-frag used by both q-subtiles)
        __builtin_amdgcn_s_setprio(1);
#pragma unroll
        for (int nt = 0; nt < 16; nt++) {
            int dbase = (nt * 16 + fr) * 64;
            f16x4 bv0 = *(const f16x4*)(Vs + dbase + vsl[0]);
            f16x4 bv1 = *(const f16x4*)(Vs + dbase + vsl[1]);
            o[0][nt] = MFMA_K16(pf[0][0], bv0, o[0][nt]);
            o[1][nt] = MFMA_K16(pf[1][0], bv0, o[1][nt]);
            o[0][nt] = MFMA_K16(pf[0][1], bv1, o[0][nt]);
            o[1][nt] = MFMA_K16(pf[1][1], bv1, o[1][nt]);
        }
        __builtin_amdgcn_s_setprio(0);
        __syncthreads();   // protect Ks/Vs before next stage / merge overlay
    }

    // ---- kh0 <-> kh1 merge (X overlays the dead K/V LDS) ----
    float l2[2];
#pragma unroll
    for (int qsub = 0; qsub < 2; qsub++) {
        float l = l_run[qsub];
        l += __shfl_xor(l, 16);
        l += __shfl_xor(l, 32);
        l2[qsub] = l;
    }
    if (lane < 16) {
#pragma unroll
        for (int qsub = 0; qsub < 2; qsub++) {
            float* mp = ML + (((rg * 2 + kh) * 2 + qsub) * 16 + lane) * 2;
            mp[0] = m_run[qsub]; mp[1] = l2[qsub];
        }
    }
    __syncthreads();
    float wr[2][4], lir[2][4];
#pragma unroll
    for (int qsub = 0; qsub < 2; qsub++) {
        const float* mp = ML + (((rg * 2 + (kh ^ 1)) * 2 + qsub) * 16 + fr) * 2;
        float mpv = mp[0], lpv = mp[1];
        float ms = fmaxf(m_run[qsub], mpv);
        float w = __expf(m_run[qsub] - ms);
        float wp = __expf(mpv - ms);
        float li = __builtin_amdgcn_rcpf(fmaxf(l2[qsub] * w + lpv * wp, 1e-30f));
#pragma unroll
        for (int r = 0; r < 4; r++) {
            wr[qsub][r] = __shfl(w, g4 + r);
            lir[qsub][r] = __shfl(li, g4 + r);
        }
    }
    if (kh == 1) {
#pragma unroll
        for (int qsub = 0; qsub < 2; qsub++)
#pragma unroll
            for (int nt = 0; nt < 16; nt++)
#pragma unroll
                for (int r = 0; r < 4; r++)
                    X[rg * 8192 + (qsub * 16 + g4 + r) * 256 + nt * 16 + fr] =
                        o[qsub][nt][r] * wr[qsub][r];
    }
    __syncthreads();
    if (kh == 0) {
#pragma unroll
        for (int qsub = 0; qsub < 2; qsub++)
#pragma unroll
            for (int nt = 0; nt < 16; nt++)
#pragma unroll
                for (int r = 0; r < 4; r++) {
                    float val = (o[qsub][nt][r] * wr[qsub][r] +
                                 X[rg * 8192 + (qsub * 16 + g4 + r) * 256 + nt * 16 + fr]) *
                                lir[qsub][r];
                    int qr = q0 + qsub * 16 + g4 + r;
                    attn[(size_t)(b * 2048 + qr) * 2048 + n * 256 + nt * 16 + fr] = f2h(val);
                }
    }
}

extern "C" void kernel_launch(void* const* d_in, const int* in_sizes, int n_in,
                              void* d_out, int out_size, void* d_ws, size_t ws_size,
                              hipStream_t stream) {
    const float* x       = (const float*)d_in[0];
    // d_in[1] = attention_mask: deterministically causal -> applied analytically
    const float* Wq      = (const float*)d_in[2];
    const float* Wk      = (const float*)d_in[3];
    const float* Wv      = (const float*)d_in[4];
    const float* Wo      = (const float*)d_in[5];
    const float* q_scale = (const float*)d_in[6];
    const float* k_scale = (const float*)d_in[7];
    float* out = (float*)d_out;
    char* ws = (char*)d_ws;

    // workspace (peak 104 MB):
    //   [0,16M):   xh fp16 -> dead after GEMM1 -> Qh fp16 [16][2048][256]
    //   [16M,32M): WT fp16 (qkv weights B^T) -> dead after GEMM1 -> Kh[16,24M) Vt[24,32M)
    //   [32M,40M): WoT fp16
    //   [40M,104M): qkv f32 4096x4096 -> dead after V-transpose -> attnb fp16 [40,56M)
    const size_t MB = 1024 * 1024;
    unsigned short* xh    = (unsigned short*)ws;
    unsigned short* Qh    = (unsigned short*)ws;
    unsigned short* WT    = (unsigned short*)(ws + 16 * MB);
    unsigned short* Kh    = (unsigned short*)(ws + 16 * MB);
    unsigned short* Vt    = (unsigned short*)(ws + 24 * MB);
    unsigned short* WoT   = (unsigned short*)(ws + 32 * MB);
    float*          qkv   = (float*)(ws + 40 * MB);
    unsigned short* attnb = (unsigned short*)(ws + 40 * MB);

    dim3 tb(32, 8);
    k_prep<<<dim3(8, 64, 25), tb, 0, stream>>>(x, Wq, Wk, Wv, Wo, xh, WT, WoT);

    k_gemm256<<<dim3(256), dim3(512), 0, stream>>>(xh, WT, qkv, 4096, 4096, 2048, 16);
    k_norm_rope<<<dim3(65536), dim3(256), 0, stream>>>(qkv, q_scale, k_scale, Qh, Kh);
    for (int b = 0; b < 2; b++)
        k_transpose_cvt<<<dim3(8, 64, 4), tb, 0, stream>>>(qkv + (size_t)b * 2048 * 4096 + 3072,
                                                           Vt + (size_t)b * 4 * 256 * 2048,
                                                           4096, 2048, 256L, 524288L);
    k_attn<<<dim3(512), dim3(256), 0, stream>>>(Qh, Kh, Vt, attnb);

    k_gemm_f16<<<dim3(16, 32), dim3(256), 0, stream>>>(attnb, WoT, out, 4096, 2048, 2048);
}